// Round 1
// baseline (210.225 us; speedup 1.0000x reference)
//
#include <hip/hip_runtime.h>

#define PSZ 16
#define BATCH 32
#define IMGH 512
#define IMGW 512
#define CH 3
#define NPATCH 1024            // patches per image (32x32)
#define M_TOT (BATCH*NPATCH)   // 32768
#define K_TOT 768
#define N_TOT 256
#define ROWSTRIDE (IMGW*CH)    // 1536 floats per image row
#define IMGSTRIDE (IMGH*IMGW*CH)

#define BM 64
#define BN 128
#define BK 64
#define KPAD 72                // padded LDS K-stride (bf16 elems): 144B rows, 2-way-only conflicts
#define NKIT (K_TOT/BK)        // 12

typedef __bf16 bf16_t;
typedef bf16_t bf16x8 __attribute__((ext_vector_type(8)));
typedef bf16_t bf16x4 __attribute__((ext_vector_type(4)));
typedef float f32x4 __attribute__((ext_vector_type(4)));

// ---------------- prep: W[768][256] fp32 -> Wt_hi/Wt_lo [256][768] bf16 ----------------
__global__ void prep_w(const float* __restrict__ Wsrc,
                       bf16_t* __restrict__ wth, bf16_t* __restrict__ wtl) {
    __shared__ float tile[32][33];
    const int d0 = blockIdx.x * 32;   // 24 tiles over K=768
    const int h0 = blockIdx.y * 32;   // 8 tiles over N=256
    const int tid = threadIdx.x;      // 256
#pragma unroll
    for (int i = 0; i < 4; ++i) {
        int idx = tid + i * 256;
        int r = idx >> 5, c = idx & 31;
        tile[r][c] = Wsrc[(d0 + r) * N_TOT + h0 + c];
    }
    __syncthreads();
#pragma unroll
    for (int i = 0; i < 4; ++i) {
        int idx = tid + i * 256;
        int r = idx >> 5, c = idx & 31;         // r: h-local, c: d-local
        float v = tile[c][r];
        bf16_t h = (bf16_t)v;
        bf16_t l = (bf16_t)(v - (float)h);
        size_t o = (size_t)(h0 + r) * K_TOT + d0 + c;
        wth[o] = h;
        wtl[o] = l;
    }
}

// ---------------- cls row: out[b,0,:] = cls + pos ----------------
__global__ void cls_add(const float* __restrict__ cls, const float* __restrict__ pos,
                        float* __restrict__ out) {
    int i = blockIdx.x * 256 + threadIdx.x;   // 8192
    int b = i >> 8, h = i & 255;
    size_t o = (size_t)b * (NPATCH + 1) * N_TOT + h;
    out[o] = cls[i] + pos[o];
}

// ---------------- main: patchify + split-bf16 MFMA GEMM + epilogue ----------------
__global__ __launch_bounds__(256, 2)
void patch_gemm(const float* __restrict__ x,
                const bf16_t* __restrict__ wth, const bf16_t* __restrict__ wtl,
                const float* __restrict__ bias, const float* __restrict__ pos,
                float* __restrict__ out) {
    __shared__ bf16_t Ah[BM * KPAD];
    __shared__ bf16_t Al[BM * KPAD];
    __shared__ bf16_t Bh[BN * KPAD];
    __shared__ bf16_t Bl[BN * KPAD];

    // bijective chunked XCD swizzle: nwg=1024 = 8 XCD * 128
    const int bid = blockIdx.x;
    const int xcd = bid & 7, kk = bid >> 3;
    const int t = xcd * 128 + kk;
    const int mtile = t >> 1;   // 0..511
    const int ntile = t & 1;    // 0..1

    const int tid = threadIdx.x;
    const int lane = tid & 63;
    const int wid = tid >> 6;
    const int wr = wid >> 1, wc = wid & 1;   // 2x2 wave grid; wave tile 32x64

    const int m0 = mtile * BM;
    const int n0 = ntile * BN;

    f32x4 acc[2][4] = {};

    const int l15 = lane & 15;
    const int kgrp = (lane >> 4) << 3;   // 0,8,16,24

    for (int kit = 0; kit < NKIT; ++kit) {
        // ---- stage A: 64 patches x 64 floats, fp32 -> hi/lo bf16 ----
#pragma unroll
        for (int i = 0; i < 4; ++i) {
            int f = tid + i * 256;           // 0..1023
            int row = f >> 4;                // 0..63
            int kl = (f & 15) << 2;          // 0..60
            int pm = m0 + row;
            int b = pm >> 10, pid = pm & 1023;
            int gr = pid >> 5, gc = pid & 31;
            int d = kit * BK + kl;           // 0..767
            int prow = d / 48;
            int poff = d % 48;
            const float* src = x + (size_t)b * IMGSTRIDE
                               + (gr * PSZ + prow) * ROWSTRIDE + gc * (PSZ * CH) + poff;
            float4 v = *(const float4*)src;
            bf16x4 hv, lv;
            hv[0] = (bf16_t)v.x; lv[0] = (bf16_t)(v.x - (float)hv[0]);
            hv[1] = (bf16_t)v.y; lv[1] = (bf16_t)(v.y - (float)hv[1]);
            hv[2] = (bf16_t)v.z; lv[2] = (bf16_t)(v.z - (float)hv[2]);
            hv[3] = (bf16_t)v.w; lv[3] = (bf16_t)(v.w - (float)hv[3]);
            int o = row * KPAD + kl;
            *reinterpret_cast<bf16x4*>(&Ah[o]) = hv;
            *reinterpret_cast<bf16x4*>(&Al[o]) = lv;
        }
        // ---- stage B: 128 cols x 64 k, bf16 hi/lo copy ----
#pragma unroll
        for (int i = 0; i < 4; ++i) {
            int f = tid + i * 256;           // 0..1023
            int row = f >> 3;                // 0..127
            int kl = (f & 7) << 3;           // 0..56
            size_t g = (size_t)(n0 + row) * K_TOT + kit * BK + kl;
            int o = row * KPAD + kl;
            *reinterpret_cast<bf16x8*>(&Bh[o]) = *reinterpret_cast<const bf16x8*>(&wth[g]);
            *reinterpret_cast<bf16x8*>(&Bl[o]) = *reinterpret_cast<const bf16x8*>(&wtl[g]);
        }
        __syncthreads();

        // ---- compute: 2 MFMA k-steps of 32 ----
#pragma unroll
        for (int ks = 0; ks < 2; ++ks) {
            const int kb = ks * 32 + kgrp;
            bf16x8 afh[2], afl[2];
#pragma unroll
            for (int ar = 0; ar < 2; ++ar) {
                int o = (wr * 32 + ar * 16 + l15) * KPAD + kb;
                afh[ar] = *reinterpret_cast<const bf16x8*>(&Ah[o]);
                afl[ar] = *reinterpret_cast<const bf16x8*>(&Al[o]);
            }
            bf16x8 bfh[4], bfl[4];
#pragma unroll
            for (int bc = 0; bc < 4; ++bc) {
                int o = (wc * 64 + bc * 16 + l15) * KPAD + kb;
                bfh[bc] = *reinterpret_cast<const bf16x8*>(&Bh[o]);
                bfl[bc] = *reinterpret_cast<const bf16x8*>(&Bl[o]);
            }
#pragma unroll
            for (int ar = 0; ar < 2; ++ar)
#pragma unroll
                for (int bc = 0; bc < 4; ++bc) {
                    acc[ar][bc] = __builtin_amdgcn_mfma_f32_16x16x32_bf16(afh[ar], bfh[bc], acc[ar][bc], 0, 0, 0);
                    acc[ar][bc] = __builtin_amdgcn_mfma_f32_16x16x32_bf16(afh[ar], bfl[bc], acc[ar][bc], 0, 0, 0);
                    acc[ar][bc] = __builtin_amdgcn_mfma_f32_16x16x32_bf16(afl[ar], bfh[bc], acc[ar][bc], 0, 0, 0);
                }
        }
        __syncthreads();
    }

    // ---- epilogue: C/D layout col=lane&15, row=(lane>>4)*4+j (m89-verified) ----
    const int colbase = n0 + wc * 64;
    float bvals[4];
#pragma unroll
    for (int bc = 0; bc < 4; ++bc) bvals[bc] = bias[colbase + bc * 16 + l15];

#pragma unroll
    for (int ar = 0; ar < 2; ++ar) {
        int rbase = m0 + wr * 32 + ar * 16 + ((lane >> 4) << 2);
#pragma unroll
        for (int j = 0; j < 4; ++j) {
            int pm = rbase + j;
            int b = pm >> 10, p = pm & 1023;
            size_t orow = (size_t)(b * (NPATCH + 1) + 1 + p) * N_TOT;
#pragma unroll
            for (int bc = 0; bc < 4; ++bc) {
                int col = colbase + bc * 16 + l15;
                out[orow + col] = acc[ar][bc][j] + bvals[bc] + pos[orow + col];
            }
        }
    }
}

extern "C" void kernel_launch(void* const* d_in, const int* in_sizes, int n_in,
                              void* d_out, int out_size, void* d_ws, size_t ws_size,
                              hipStream_t stream) {
    const float* x    = (const float*)d_in[0];
    const float* W    = (const float*)d_in[1];
    const float* bias = (const float*)d_in[2];
    const float* cls  = (const float*)d_in[3];
    const float* pos  = (const float*)d_in[4];
    float* out = (float*)d_out;

    bf16_t* wth = (bf16_t*)d_ws;
    bf16_t* wtl = wth + (size_t)K_TOT * N_TOT;

    prep_w<<<dim3(24, 8), 256, 0, stream>>>(W, wth, wtl);
    cls_add<<<32, 256, 0, stream>>>(cls, pos, out);
    patch_gemm<<<1024, 256, 0, stream>>>(x, wth, wtl, bias, pos, out);
}